// Round 14
// baseline (222.709 us; speedup 1.0000x reference)
//
#include <hip/hip_runtime.h>

#define C1 128   // heads1(4) * hid(32)
#define C2 64    // out channels layer 2
#define CAP 96   // per-dst bucket capacity; P(Poisson(16) > 96) < 1e-40
#define NBF 2048 // fill-partition blocks in the merged gemm1+fill dispatch

typedef __attribute__((ext_vector_type(8))) _Float16 half8;
typedef __attribute__((ext_vector_type(2))) _Float16 half2v;
typedef __attribute__((ext_vector_type(2))) __fp16  fp16x2;   // cvt_pkrtz return type
typedef __attribute__((ext_vector_type(4))) float floatx4;
typedef __attribute__((ext_vector_type(4))) int   intx4;      // nt-load-compatible

__device__ __forceinline__ float lrelu(float v) { return v > 0.f ? v : 0.2f * v; }

// pack 2 fp32 -> 2 f16 (v_cvt_pkrtz_f16_f32, 1 instr)
__device__ __forceinline__ unsigned pk2h(float a, float b) {
    union { fp16x2 p; unsigned u; } c;
    c.p = __builtin_amdgcn_cvt_pkrtz(a, b);
    return c.u;
}

// ---------------- prep: zero cursor + pre-convert W1 to f16 pair-packed col-major ----------------
// W1c[col*64 + j] = f16 pair (W1[2j][col], W1[2j+1][col]). A gemm1 B-fragment
// (col, quad, kk) = k in [quad*8+kk*32, +8) is then dwords [quad*4+kk*16, +4) of
// column col -> one contiguous 16B global load. 32KB total, L1/L2-resident.
__global__ __launch_bounds__(256)
void prep_kernel(const float* __restrict__ W1, unsigned* __restrict__ w1c,
                 int* __restrict__ cursor, int N) {
    const int t = blockIdx.x * 256 + threadIdx.x;
    for (int i = t; i < N; i += gridDim.x * 256) cursor[i] = 0;
    if (t < 128 * 64) {
        const int col = t >> 6, j = t & 63;
        w1c[col * 64 + j] = pk2h(W1[(2 * j) * 128 + col], W1[(2 * j + 1) * 128 + col]);
    }
}

// ---------------- MERGED Layer-1 GEMM + CSR fill, ZERO LDS (r12) ----------------
// r13 changes: (a) ei and x loads are NON-TEMPORAL (ext_vector types; HIP_vector_type
// rejected by the builtin) -> streaming reads stop evicting csrc's partially-dirty
// L2 lines (r12: WRITE_SIZE 62MB vs ~18MB useful = scatter amplification);
// (b) csrc is u16 (src < N=50000 < 65536, guard enforces) -> csrc slice
// 2.4->1.2MB/XCD, better L2 residency.
// h1 dword layout: dword p of a row holds f16 pair (ch 32*(p>>4)+(p&15), +16).
__global__ __launch_bounds__(256)
void gemm1_fill_kernel(const float* __restrict__ x, const unsigned* __restrict__ w1c,
                       const float* __restrict__ asrc, const float* __restrict__ adst,
                       unsigned* __restrict__ h1d,
                       float* __restrict__ as1, float* __restrict__ ad1,
                       const int* __restrict__ ei, int* __restrict__ cursor,
                       unsigned short* __restrict__ csrc, int nbTile, int N, int E) {
    if ((int)blockIdx.x >= nbTile) {
        // ---------------- fill partition ----------------
        const int b    = blockIdx.x - nbTile;
        const int part = b & 7;
        const int bIdx = b >> 3;
        const int bpp  = NBF >> 3;
        const int lo = (int)(((long)N * part) >> 3);
        const int hi = (int)(((long)N * (part + 1)) >> 3);

        const int E4 = ((E & 3) == 0) ? (E >> 2) : 0;
        const intx4* d4 = (const intx4*)(ei + E);
        const intx4* s4 = (const intx4*)ei;
        for (int q = bIdx * 256 + threadIdx.x; q < E4; q += bpp * 256) {
            intx4 dv = __builtin_nontemporal_load(&d4[q]);   // streaming: keep out of L2
            intx4 sv = __builtin_nontemporal_load(&s4[q]);
            int dd[4] = {dv.x, dv.y, dv.z, dv.w};
            int ss[4] = {sv.x, sv.y, sv.z, sv.w};
            int pos[4];
            bool act[4];
#pragma unroll
            for (int i = 0; i < 4; ++i) {
                act[i] = (dd[i] >= lo) & (dd[i] < hi) & ((unsigned)ss[i] < (unsigned)N);
                pos[i] = act[i] ? atomicAdd(&cursor[dd[i]], 1) : 0;   // 4 atomics in flight
            }
#pragma unroll
            for (int i = 0; i < 4; ++i)
                if (act[i] && pos[i] < CAP) csrc[dd[i] * CAP + pos[i]] = (unsigned short)ss[i];
        }
        for (int e = E4 * 4 + bIdx * 256 + threadIdx.x; e < E; e += bpp * 256) {
            int dd = ei[E + e];
            if (dd < lo || dd >= hi) continue;
            int ss = ei[e];
            if ((unsigned)ss >= (unsigned)N) continue;
            int pp = atomicAdd(&cursor[dd], 1);
            if (pp < CAP) csrc[dd * CAP + pp] = (unsigned short)ss;
        }
        return;
    }

    // ---------------- gemm1 partition (r5-proven math; B from W1c, no LDS) ----------------
    const int lane = threadIdx.x & 63, ww = threadIdx.x >> 6;
    const int quad = lane >> 4, l16 = lane & 15;
    const int nodeBase = blockIdx.x * 64 + ww * 16;
    int arow = nodeBase + l16;
    if (arow >= N) arow = N - 1;                       // clamp loads; stores guarded
    const float* xp = x + (size_t)arow * C1 + quad * 8;
    half8 afr[4];
#pragma unroll
    for (int kk = 0; kk < 4; ++kk) {
        floatx4 a0 = __builtin_nontemporal_load((const floatx4*)(xp + kk * 32));
        floatx4 a1 = __builtin_nontemporal_load((const floatx4*)(xp + kk * 32 + 4));
        union { half8 v; unsigned u[4]; } fr;
        fr.u[0] = pk2h(a0.x, a0.y);
        fr.u[1] = pk2h(a0.z, a0.w);
        fr.u[2] = pk2h(a1.x, a1.y);
        fr.u[3] = pk2h(a1.z, a1.w);
        afr[kk] = fr.v;
    }

#pragma unroll
    for (int h = 0; h < 4; ++h) {
        floatx4 accL = {0.f, 0.f, 0.f, 0.f};
        floatx4 accH = {0.f, 0.f, 0.f, 0.f};
        const int colL = h * 32 + l16;          // ct = 2h
        const int colH = colL + 16;             // ct = 2h+1, same head h
        const unsigned* bLp = w1c + colL * 64 + quad * 4;
        const unsigned* bHp = w1c + colH * 64 + quad * 4;
#pragma unroll
        for (int kk = 0; kk < 4; ++kk) {
            half8 bfrL = *(const half8*)(bLp + kk * 16);   // 16B contiguous, L1-hit
            half8 bfrH = *(const half8*)(bHp + kk * 16);
            accL = __builtin_amdgcn_mfma_f32_16x16x32_f16(afr[kk], bfrL, accL, 0, 0, 0);
            accH = __builtin_amdgcn_mfma_f32_16x16x32_f16(afr[kk], bfrH, accH, 0, 0, 0);
        }
        // C/D layout: col=lane&15, row=quad*4+reg  [m89/m91 verified]
#pragma unroll
        for (int reg = 0; reg < 4; ++reg) {
            int node = nodeBase + quad * 4 + reg;
            if (node < N) h1d[(size_t)node * 64 + h * 16 + l16] = pk2h(accL[reg], accH[reg]);
        }
        float avL = asrc[colL], dvL = adst[colL];
        float avH = asrc[colH], dvH = adst[colH];
#pragma unroll
        for (int reg = 0; reg < 4; ++reg) {
            float ts = accL[reg] * avL + accH[reg] * avH;
            float td = accL[reg] * dvL + accH[reg] * dvH;
#pragma unroll
            for (int o = 1; o < 16; o <<= 1) {
                ts += __shfl_xor(ts, o, 64);
                td += __shfl_xor(td, o, 64);
            }
            if (l16 == 0) {
                int node = nodeBase + quad * 4 + reg;
                if (node < N) {
                    as1[node * 4 + h] = ts;
                    ad1[node * 4 + h] = td;
                }
            }
        }
    }
}

// ---------------- Layer 1 CSR gather v8 (r5-proven, 44.2 us): one dst per wave ----------------
// lane l handles channels (32*head + e16, 32*head + e16 + 16), head = l>>4, e16 = l&15.
__global__ __launch_bounds__(256)
void msg1_csr_kernel(const int* __restrict__ cursor, const unsigned short* __restrict__ csrc,
                     const unsigned* __restrict__ h1u, const float* __restrict__ as1,
                     const float* __restrict__ ad1, const float* __restrict__ b1,
                     unsigned* __restrict__ out1, int N) {
    __shared__ float ws[4][64];
    const int wid = threadIdx.x >> 6;
    const int d = blockIdx.x * 4 + wid;
    if (d >= N) return;
    const int lane = threadIdx.x & 63;
    const int e16 = lane & 15;
    const int head = lane >> 4;
    int dg = cursor[d]; if (dg > CAP) dg = CAP;
    const int base = d * CAP;
    const float wadh = ad1[d * 4 + head];
    float accx = 0.f, accy = 0.f, sumw = 0.f;
    for (int jj = 0; jj < dg; jj += 16) {
        int idx = jj + e16;
        if (idx >= dg) idx = dg - 1;
        const int myS = csrc[base + idx];            // u16 zero-extends
        // gather: SGPR row base per source via readlane (lanes 0-15 hold the 16 sources)
        unsigned rv[16];
#pragma unroll
        for (int k = 0; k < 16; ++k) {
            int s = __builtin_amdgcn_readlane(myS, k);
            rv[k] = h1u[(unsigned)s * 64u + (unsigned)lane];
        }
        float w = 0.f;
        if (jj + e16 < dg)
            w = __expf(lrelu(as1[myS * 4 + head] + wadh));
        ws[wid][lane] = w;                 // w[head][e16]; same-wave LDS broadcast
#pragma unroll
        for (int j = 0; j < 4; ++j) {
            float4 wf = ((const float4*)&ws[wid][head * 16])[j];
            union { unsigned u; half2v p; } c0, c1, c2, c3;
            c0.u = rv[4 * j + 0]; c1.u = rv[4 * j + 1];
            c2.u = rv[4 * j + 2]; c3.u = rv[4 * j + 3];
            sumw += (wf.x + wf.y) + (wf.z + wf.w);
            accx += wf.x * (float)c0.p[0]; accy += wf.x * (float)c0.p[1];
            accx += wf.y * (float)c1.p[0]; accy += wf.y * (float)c1.p[1];
            accx += wf.z * (float)c2.p[0]; accy += wf.z * (float)c2.p[1];
            accx += wf.w * (float)c3.p[0]; accy += wf.w * (float)c3.p[1];
        }
    }
    float inv = (sumw > 0.f) ? 1.f / sumw : 0.f;
    float rx = accx * inv + b1[32 * head + e16];
    float ry = accy * inv + b1[32 * head + e16 + 16];
    rx = rx > 0.f ? rx : expm1f(rx);
    ry = ry > 0.f ? ry : expm1f(ry);
    out1[(size_t)d * 64 + lane] = pk2h(rx, ry);   // keeps (c, c+16)-pair layout
}

// ---------------- Layer 2 GEMM (r5-proven): f16 in, K-permuted B staging ----------------
// A (= out1) dword p holds channels (32*(p>>4)+(p&15), +16); Bs is staged with the
// identical K-permutation so the contraction is unchanged. g2 output packs cols
// (c, c+32) into dword c (c in [0,32)).
__global__ __launch_bounds__(256)
void gemm2_mfma_kernel(const unsigned short* __restrict__ h2, const float* __restrict__ W2,
                       const float* __restrict__ asrc, const float* __restrict__ adst,
                       unsigned* __restrict__ g2d, float* __restrict__ as2,
                       float* __restrict__ ad2, int N) {
    __shared__ __align__(16) unsigned short Bs[64 * 136];
    for (int i = threadIdx.x; i < 64 * 64; i += 256) {
        int col = i & 63;
        int p = i >> 6;                          // dword index along K
        int k0 = 32 * (p >> 4) + (p & 15);       // matches out1's channel pairing
        *(unsigned*)&Bs[col * 136 + 2 * p] = pk2h(W2[k0 * 64 + col], W2[(k0 + 16) * 64 + col]);
    }
    __syncthreads();

    const int lane = threadIdx.x & 63, ww = threadIdx.x >> 6;
    const int quad = lane >> 4, l16 = lane & 15;
    const int nodeBase = blockIdx.x * 64 + ww * 16;
    int arow = nodeBase + l16;
    if (arow >= N) arow = N - 1;
    const unsigned short* xp = h2 + (size_t)arow * C1 + quad * 8;
    half8 afr[4];
#pragma unroll
    for (int kk = 0; kk < 4; ++kk)
        afr[kk] = *(const half8*)(xp + kk * 32);   // direct f16 fragment, no cvt

    float sacc[4] = {0.f,0.f,0.f,0.f}, dacc[4] = {0.f,0.f,0.f,0.f};
#pragma unroll
    for (int ctp = 0; ctp < 2; ++ctp) {
        floatx4 accL = {0.f, 0.f, 0.f, 0.f};
        floatx4 accH = {0.f, 0.f, 0.f, 0.f};
        const int colL = ctp * 16 + l16;         // in [0,32)
        const int colH = colL + 32;
        const unsigned short* bL = &Bs[colL * 136 + quad * 8];
        const unsigned short* bH = &Bs[colH * 136 + quad * 8];
#pragma unroll
        for (int kk = 0; kk < 4; ++kk) {
            half8 bfrL = *(const half8*)(bL + kk * 32);
            half8 bfrH = *(const half8*)(bH + kk * 32);
            accL = __builtin_amdgcn_mfma_f32_16x16x32_f16(afr[kk], bfrL, accL, 0, 0, 0);
            accH = __builtin_amdgcn_mfma_f32_16x16x32_f16(afr[kk], bfrH, accH, 0, 0, 0);
        }
#pragma unroll
        for (int reg = 0; reg < 4; ++reg) {
            int node = nodeBase + quad * 4 + reg;
            if (node < N) g2d[(size_t)node * 32 + colL] = pk2h(accL[reg], accH[reg]);
        }
        float avL = asrc[colL], dvL = adst[colL];
        float avH = asrc[colH], dvH = adst[colH];
#pragma unroll
        for (int reg = 0; reg < 4; ++reg) {
            sacc[reg] += accL[reg] * avL + accH[reg] * avH;
            dacc[reg] += accL[reg] * dvL + accH[reg] * dvH;
        }
    }
#pragma unroll
    for (int reg = 0; reg < 4; ++reg) {
        float ts = sacc[reg], td = dacc[reg];
#pragma unroll
        for (int o = 1; o < 16; o <<= 1) {
            ts += __shfl_xor(ts, o, 64);
            td += __shfl_xor(td, o, 64);
        }
        if (l16 == 0) {
            int node = nodeBase + quad * 4 + reg;
            if (node < N) { as2[node] = ts; ad2[node] = td; }
        }
    }
}

// ---------------- Layer 2 CSR gather v8 (r5-proven): one dst per wave, 32-edge strips ----------------
// g2 dword l32 holds channels (l32, l32+32); final store writes the two coalesced
// 128B float halves of the output row directly.
__global__ __launch_bounds__(256)
void msg2_csr_kernel(const int* __restrict__ cursor, const unsigned short* __restrict__ csrc,
                     const unsigned* __restrict__ g2u, const float* __restrict__ as2,
                     const float* __restrict__ ad2, const float* __restrict__ b2,
                     float* __restrict__ yf, int N) {
    __shared__ float wsm[4][32];
    __shared__ int   ssm[4][32];
    const int wid = threadIdx.x >> 6;
    const int d = blockIdx.x * 4 + wid;
    if (d >= N) return;
    const int lane = threadIdx.x & 63;
    const int half = lane >> 5;
    const int l32 = lane & 31;
    int dg = cursor[d]; if (dg > CAP) dg = CAP;
    const int base = d * CAP;
    const float add = ad2[d];
    float accx = 0.f, accy = 0.f, sumw = 0.f;
    for (int jj = 0; jj < dg; jj += 32) {
        int idx = jj + l32;
        if (idx >= dg) idx = dg - 1;
        const int myS = csrc[base + idx];            // u16 zero-extends
        // all 64 lanes compute (both halves produce identical values -> benign dup write)
        float w = 0.f;
        if (jj + l32 < dg) w = __expf(lrelu(as2[myS] + add));
        ssm[wid][l32] = myS;
        wsm[wid][l32] = w;
        int4 s0 = ((const int4*)&ssm[wid][half * 16])[0];
        int4 s1 = ((const int4*)&ssm[wid][half * 16])[1];
        int4 s2 = ((const int4*)&ssm[wid][half * 16])[2];
        int4 s3 = ((const int4*)&ssm[wid][half * 16])[3];
        int ss[16] = {s0.x, s0.y, s0.z, s0.w, s1.x, s1.y, s1.z, s1.w,
                      s2.x, s2.y, s2.z, s2.w, s3.x, s3.y, s3.z, s3.w};
        unsigned rv[16];
#pragma unroll
        for (int k = 0; k < 16; ++k)
            rv[k] = g2u[(unsigned)ss[k] * 32u + (unsigned)l32];
#pragma unroll
        for (int j = 0; j < 4; ++j) {
            float4 wf = ((const float4*)&wsm[wid][half * 16])[j];
            union { unsigned u; half2v p; } c0, c1, c2, c3;
            c0.u = rv[4 * j + 0]; c1.u = rv[4 * j + 1];
            c2.u = rv[4 * j + 2]; c3.u = rv[4 * j + 3];
            sumw += (wf.x + wf.y) + (wf.z + wf.w);
            accx += wf.x * (float)c0.p[0]; accy += wf.x * (float)c0.p[1];
            accx += wf.y * (float)c1.p[0]; accy += wf.y * (float)c1.p[1];
            accx += wf.z * (float)c2.p[0]; accy += wf.z * (float)c2.p[1];
            accx += wf.w * (float)c3.p[0]; accy += wf.w * (float)c3.p[1];
        }
    }
    accx += __shfl_xor(accx, 32, 64);
    accy += __shfl_xor(accy, 32, 64);
    sumw += __shfl_xor(sumw, 32, 64);
    if (half == 0) {
        float inv = (sumw > 0.f) ? 1.f / sumw : 0.f;
        yf[(size_t)d * 64 + l32]      = accx * inv + b2[l32];        // ch l32
        yf[(size_t)d * 64 + 32 + l32] = accy * inv + b2[l32 + 32];   // ch l32+32
    }
}

extern "C" void kernel_launch(void* const* d_in, const int* in_sizes, int n_in,
                              void* d_out, int out_size, void* d_ws, size_t ws_size,
                              hipStream_t stream) {
    const float* x    = (const float*)d_in[0];
    const int*   ei   = (const int*)d_in[1];
    const float* W1   = (const float*)d_in[2];
    const float* a_s1 = (const float*)d_in[3];
    const float* a_d1 = (const float*)d_in[4];
    const float* b1   = (const float*)d_in[5];
    const float* W2   = (const float*)d_in[6];
    const float* a_s2 = (const float*)d_in[7];
    const float* a_d2 = (const float*)d_in[8];
    const float* b2   = (const float*)d_in[9];

    const int N = in_sizes[0] / C1;
    const int E = in_sizes[1] / 2;

    auto align16 = [](size_t v) { return (v + 15) & ~(size_t)15; };
    const size_t RF   = 16;
    const size_t RCUR = align16((size_t)N * 4);           // cursor / degree
    const size_t RSRC = align16((size_t)N * CAP * 2);     // bucketed csrc (u16)
    const size_t RW1  = 128 * 64 * 4;                     // W1c: f16-pair dwords [128 cols][64]
    const size_t R1   = align16((size_t)N * C1 * 4);      // h1/g2 region
    const size_t R2   = align16((size_t)N * 8 * 4);       // as1+ad1 / as2+ad2

    char* base = (char*)d_ws;
    int*  cursor = (int*)(base + RF);
    unsigned short* csrc = (unsigned short*)(base + RF + RCUR);
    unsigned* w1c = (unsigned*)(base + RF + RCUR + RSRC);
    char* R1p = base + RF + RCUR + RSRC + RW1;
    char* R2p = R1p + R1;
    char* R4p = R2p + R2;
    (void)ws_size;

    unsigned* h1 = (unsigned*)R1p;               // f16-pair dwords [N,64]
    unsigned* g2 = (unsigned*)R1p;               // f16-pair dwords [N,32] (h1 dead after msg1)
    float* as1 = (float*)R2p;
    float* ad1 = as1 + (size_t)N * 4;
    float* as2 = (float*)R2p;                    // as1/ad1 dead after msg1
    float* ad2 = as2 + N;
    unsigned* out1 = (unsigned*)R4p;             // f16-pair dwords [N,64]

    const int nbTile = (N + 63) / 64;
    const int nbWave4 = (N + 3) / 4;

    prep_kernel<<<256, 256, 0, stream>>>(W1, w1c, cursor, N);
    gemm1_fill_kernel<<<nbTile + NBF, 256, 0, stream>>>(x, w1c, a_s1, a_d1, h1,
        as1, ad1, ei, cursor, csrc, nbTile, N, E);
    msg1_csr_kernel<<<nbWave4, 256, 0, stream>>>(cursor, csrc, (const unsigned*)h1,
        as1, ad1, b1, out1, N);
    gemm2_mfma_kernel<<<nbTile, 256, 0, stream>>>((const unsigned short*)out1, W2,
        a_s2, a_d2, g2, as2, ad2, N);
    msg2_csr_kernel<<<nbWave4, 256, 0, stream>>>(cursor, csrc, (const unsigned*)g2,
        as2, ad2, b2, (float*)d_out, N);
}

// Round 15
// 206.834 us; speedup vs baseline: 1.0768x; 1.0768x over previous
//
#include <hip/hip_runtime.h>

#define C1 128   // heads1(4) * hid(32)
#define C2 64    // out channels layer 2
#define CAP 96   // per-dst bucket capacity; P(Poisson(16) > 96) < 1e-40
#define NBF 2048 // fill-partition blocks in the merged gemm1+fill dispatch

typedef __attribute__((ext_vector_type(8))) _Float16 half8;
typedef __attribute__((ext_vector_type(2))) _Float16 half2v;
typedef __attribute__((ext_vector_type(2))) __fp16  fp16x2;   // cvt_pkrtz return type
typedef __attribute__((ext_vector_type(4))) float floatx4;

__device__ __forceinline__ float lrelu(float v) { return v > 0.f ? v : 0.2f * v; }

// pack 2 fp32 -> 2 f16 (v_cvt_pkrtz_f16_f32, 1 instr)
__device__ __forceinline__ unsigned pk2h(float a, float b) {
    union { fp16x2 p; unsigned u; } c;
    c.p = __builtin_amdgcn_cvt_pkrtz(a, b);
    return c.u;
}

// ---------------- MERGED: Layer 1 GEMM (blocks [0,nbTile)) + CSR fill (blocks [nbTile,nbTile+NBF)) ----------------
// r8-proven configuration (207.2 us total). The two phases are data-independent
// (x,W1 vs ei); merging removes one serial dispatch boundary; the tail of gemm1
// blocks overlaps the head of fill blocks at the dispatch seam.
// h1 dword layout: dword p of a row holds f16 pair (ch 32*(p>>4)+(p&15), +16).
__global__ __launch_bounds__(256)
void gemm1_fill_kernel(const float* __restrict__ x, const float* __restrict__ W1,
                       const float* __restrict__ asrc, const float* __restrict__ adst,
                       unsigned* __restrict__ h1d,
                       float* __restrict__ as1, float* __restrict__ ad1,
                       const int* __restrict__ ei, int* __restrict__ cursor,
                       int* __restrict__ csrc, int nbTile, int N, int E) {
    if ((int)blockIdx.x >= nbTile) {
        // ---------------- fill partition (r1-proven body; local block index) ----------------
        const int b    = blockIdx.x - nbTile;
        const int part = b & 7;
        const int bIdx = b >> 3;
        const int bpp  = NBF >> 3;
        const int lo = (int)(((long)N * part) >> 3);
        const int hi = (int)(((long)N * (part + 1)) >> 3);

        const int E4 = ((E & 3) == 0) ? (E >> 2) : 0;
        const int4* d4 = (const int4*)(ei + E);
        const int4* s4 = (const int4*)ei;
        for (int q = bIdx * 256 + threadIdx.x; q < E4; q += bpp * 256) {
            int4 dv = d4[q];
            int4 sv = s4[q];
            int dd[4] = {dv.x, dv.y, dv.z, dv.w};
            int ss[4] = {sv.x, sv.y, sv.z, sv.w};
            int pos[4];
            bool act[4];
#pragma unroll
            for (int i = 0; i < 4; ++i) {
                act[i] = (dd[i] >= lo) & (dd[i] < hi) & ((unsigned)ss[i] < (unsigned)N);
                pos[i] = act[i] ? atomicAdd(&cursor[dd[i]], 1) : 0;   // 4 atomics in flight
            }
#pragma unroll
            for (int i = 0; i < 4; ++i)
                if (act[i] && pos[i] < CAP) csrc[dd[i] * CAP + pos[i]] = ss[i];
        }
        for (int e = E4 * 4 + bIdx * 256 + threadIdx.x; e < E; e += bpp * 256) {
            int dd = ei[E + e];
            if (dd < lo || dd >= hi) continue;
            int ss = ei[e];
            if ((unsigned)ss >= (unsigned)N) continue;
            int pp = atomicAdd(&cursor[dd], 1);
            if (pp < CAP) csrc[dd * CAP + pp] = ss;
        }
        return;
    }

    // ---------------- gemm1 partition (r5-proven body) ----------------
    __shared__ __align__(16) unsigned short Bs[128 * 136];
    for (int i = threadIdx.x; i < 128 * 64; i += 256) {
        int col = i & 127;
        int k = (i >> 7) * 2;
        *(unsigned*)&Bs[col * 136 + k] = pk2h(W1[k * 128 + col], W1[(k + 1) * 128 + col]);
    }
    __syncthreads();

    const int lane = threadIdx.x & 63, ww = threadIdx.x >> 6;
    const int quad = lane >> 4, l16 = lane & 15;
    const int nodeBase = blockIdx.x * 64 + ww * 16;
    int arow = nodeBase + l16;
    if (arow >= N) arow = N - 1;                       // clamp loads; stores guarded
    const float* xp = x + (size_t)arow * C1 + quad * 8;
    half8 afr[4];
#pragma unroll
    for (int kk = 0; kk < 4; ++kk) {
        float4 a0 = *(const float4*)(xp + kk * 32);
        float4 a1 = *(const float4*)(xp + kk * 32 + 4);
        union { half8 v; unsigned u[4]; } fr;
        fr.u[0] = pk2h(a0.x, a0.y);
        fr.u[1] = pk2h(a0.z, a0.w);
        fr.u[2] = pk2h(a1.x, a1.y);
        fr.u[3] = pk2h(a1.z, a1.w);
        afr[kk] = fr.v;
    }

#pragma unroll
    for (int h = 0; h < 4; ++h) {
        floatx4 accL = {0.f, 0.f, 0.f, 0.f};
        floatx4 accH = {0.f, 0.f, 0.f, 0.f};
        const int colL = h * 32 + l16;          // ct = 2h
        const int colH = colL + 16;             // ct = 2h+1, same head h
        const unsigned short* bL = &Bs[colL * 136 + quad * 8];
        const unsigned short* bH = &Bs[colH * 136 + quad * 8];
#pragma unroll
        for (int kk = 0; kk < 4; ++kk) {
            half8 bfrL = *(const half8*)(bL + kk * 32);
            half8 bfrH = *(const half8*)(bH + kk * 32);
            accL = __builtin_amdgcn_mfma_f32_16x16x32_f16(afr[kk], bfrL, accL, 0, 0, 0);
            accH = __builtin_amdgcn_mfma_f32_16x16x32_f16(afr[kk], bfrH, accH, 0, 0, 0);
        }
        // C/D layout: col=lane&15, row=quad*4+reg  [m89/m91 verified]
#pragma unroll
        for (int reg = 0; reg < 4; ++reg) {
            int node = nodeBase + quad * 4 + reg;
            if (node < N) h1d[(size_t)node * 64 + h * 16 + l16] = pk2h(accL[reg], accH[reg]);
        }
        float avL = asrc[colL], dvL = adst[colL];
        float avH = asrc[colH], dvH = adst[colH];
#pragma unroll
        for (int reg = 0; reg < 4; ++reg) {
            float ts = accL[reg] * avL + accH[reg] * avH;
            float td = accL[reg] * dvL + accH[reg] * dvH;
#pragma unroll
            for (int o = 1; o < 16; o <<= 1) {
                ts += __shfl_xor(ts, o, 64);
                td += __shfl_xor(td, o, 64);
            }
            if (l16 == 0) {
                int node = nodeBase + quad * 4 + reg;
                if (node < N) {
                    as1[node * 4 + h] = ts;
                    ad1[node * 4 + h] = td;
                }
            }
        }
    }
}

// ---------------- Layer 1 CSR gather v8 (r5-proven, 44.2 us): one dst per wave ----------------
// lane l handles channels (32*head + e16, 32*head + e16 + 16), head = l>>4, e16 = l&15.
__global__ __launch_bounds__(256)
void msg1_csr_kernel(const int* __restrict__ cursor, const int* __restrict__ csrc,
                     const unsigned* __restrict__ h1u, const float* __restrict__ as1,
                     const float* __restrict__ ad1, const float* __restrict__ b1,
                     unsigned* __restrict__ out1, int N) {
    __shared__ float ws[4][64];
    const int wid = threadIdx.x >> 6;
    const int d = blockIdx.x * 4 + wid;
    if (d >= N) return;
    const int lane = threadIdx.x & 63;
    const int e16 = lane & 15;
    const int head = lane >> 4;
    int dg = cursor[d]; if (dg > CAP) dg = CAP;
    const int base = d * CAP;
    const float wadh = ad1[d * 4 + head];
    float accx = 0.f, accy = 0.f, sumw = 0.f;
    for (int jj = 0; jj < dg; jj += 16) {
        int idx = jj + e16;
        if (idx >= dg) idx = dg - 1;
        const int myS = csrc[base + idx];
        // gather: SGPR row base per source via readlane (lanes 0-15 hold the 16 sources)
        unsigned rv[16];
#pragma unroll
        for (int k = 0; k < 16; ++k) {
            int s = __builtin_amdgcn_readlane(myS, k);
            rv[k] = h1u[(unsigned)s * 64u + (unsigned)lane];
        }
        float w = 0.f;
        if (jj + e16 < dg)
            w = __expf(lrelu(as1[myS * 4 + head] + wadh));
        ws[wid][lane] = w;                 // w[head][e16]; same-wave LDS broadcast
#pragma unroll
        for (int j = 0; j < 4; ++j) {
            float4 wf = ((const float4*)&ws[wid][head * 16])[j];
            union { unsigned u; half2v p; } c0, c1, c2, c3;
            c0.u = rv[4 * j + 0]; c1.u = rv[4 * j + 1];
            c2.u = rv[4 * j + 2]; c3.u = rv[4 * j + 3];
            sumw += (wf.x + wf.y) + (wf.z + wf.w);
            accx += wf.x * (float)c0.p[0]; accy += wf.x * (float)c0.p[1];
            accx += wf.y * (float)c1.p[0]; accy += wf.y * (float)c1.p[1];
            accx += wf.z * (float)c2.p[0]; accy += wf.z * (float)c2.p[1];
            accx += wf.w * (float)c3.p[0]; accy += wf.w * (float)c3.p[1];
        }
    }
    float inv = (sumw > 0.f) ? 1.f / sumw : 0.f;
    float rx = accx * inv + b1[32 * head + e16];
    float ry = accy * inv + b1[32 * head + e16 + 16];
    rx = rx > 0.f ? rx : expm1f(rx);
    ry = ry > 0.f ? ry : expm1f(ry);
    out1[(size_t)d * 64 + lane] = pk2h(rx, ry);   // keeps (c, c+16)-pair layout
}

// ---------------- Layer 2 GEMM (r5-proven): f16 in, K-permuted B staging ----------------
// A (= out1) dword p holds channels (32*(p>>4)+(p&15), +16); Bs is staged with the
// identical K-permutation so the contraction is unchanged. g2 output packs cols
// (c, c+32) into dword c (c in [0,32)).
__global__ __launch_bounds__(256)
void gemm2_mfma_kernel(const unsigned short* __restrict__ h2, const float* __restrict__ W2,
                       const float* __restrict__ asrc, const float* __restrict__ adst,
                       unsigned* __restrict__ g2d, float* __restrict__ as2,
                       float* __restrict__ ad2, int N) {
    __shared__ __align__(16) unsigned short Bs[64 * 136];
    for (int i = threadIdx.x; i < 64 * 64; i += 256) {
        int col = i & 63;
        int p = i >> 6;                          // dword index along K
        int k0 = 32 * (p >> 4) + (p & 15);       // matches out1's channel pairing
        *(unsigned*)&Bs[col * 136 + 2 * p] = pk2h(W2[k0 * 64 + col], W2[(k0 + 16) * 64 + col]);
    }
    __syncthreads();

    const int lane = threadIdx.x & 63, ww = threadIdx.x >> 6;
    const int quad = lane >> 4, l16 = lane & 15;
    const int nodeBase = blockIdx.x * 64 + ww * 16;
    int arow = nodeBase + l16;
    if (arow >= N) arow = N - 1;
    const unsigned short* xp = h2 + (size_t)arow * C1 + quad * 8;
    half8 afr[4];
#pragma unroll
    for (int kk = 0; kk < 4; ++kk)
        afr[kk] = *(const half8*)(xp + kk * 32);   // direct f16 fragment, no cvt

    float sacc[4] = {0.f,0.f,0.f,0.f}, dacc[4] = {0.f,0.f,0.f,0.f};
#pragma unroll
    for (int ctp = 0; ctp < 2; ++ctp) {
        floatx4 accL = {0.f, 0.f, 0.f, 0.f};
        floatx4 accH = {0.f, 0.f, 0.f, 0.f};
        const int colL = ctp * 16 + l16;         // in [0,32)
        const int colH = colL + 32;
        const unsigned short* bL = &Bs[colL * 136 + quad * 8];
        const unsigned short* bH = &Bs[colH * 136 + quad * 8];
#pragma unroll
        for (int kk = 0; kk < 4; ++kk) {
            half8 bfrL = *(const half8*)(bL + kk * 32);
            half8 bfrH = *(const half8*)(bH + kk * 32);
            accL = __builtin_amdgcn_mfma_f32_16x16x32_f16(afr[kk], bfrL, accL, 0, 0, 0);
            accH = __builtin_amdgcn_mfma_f32_16x16x32_f16(afr[kk], bfrH, accH, 0, 0, 0);
        }
#pragma unroll
        for (int reg = 0; reg < 4; ++reg) {
            int node = nodeBase + quad * 4 + reg;
            if (node < N) g2d[(size_t)node * 32 + colL] = pk2h(accL[reg], accH[reg]);
        }
        float avL = asrc[colL], dvL = adst[colL];
        float avH = asrc[colH], dvH = adst[colH];
#pragma unroll
        for (int reg = 0; reg < 4; ++reg) {
            sacc[reg] += accL[reg] * avL + accH[reg] * avH;
            dacc[reg] += accL[reg] * dvL + accH[reg] * dvH;
        }
    }
#pragma unroll
    for (int reg = 0; reg < 4; ++reg) {
        float ts = sacc[reg], td = dacc[reg];
#pragma unroll
        for (int o = 1; o < 16; o <<= 1) {
            ts += __shfl_xor(ts, o, 64);
            td += __shfl_xor(td, o, 64);
        }
        if (l16 == 0) {
            int node = nodeBase + quad * 4 + reg;
            if (node < N) { as2[node] = ts; ad2[node] = td; }
        }
    }
}

// ---------------- Layer 2 CSR gather v8 (r5-proven): one dst per wave, 32-edge strips ----------------
// g2 dword l32 holds channels (l32, l32+32); final store writes the two coalesced
// 128B float halves of the output row directly.
__global__ __launch_bounds__(256)
void msg2_csr_kernel(const int* __restrict__ cursor, const int* __restrict__ csrc,
                     const unsigned* __restrict__ g2u, const float* __restrict__ as2,
                     const float* __restrict__ ad2, const float* __restrict__ b2,
                     float* __restrict__ yf, int N) {
    __shared__ float wsm[4][32];
    __shared__ int   ssm[4][32];
    const int wid = threadIdx.x >> 6;
    const int d = blockIdx.x * 4 + wid;
    if (d >= N) return;
    const int lane = threadIdx.x & 63;
    const int half = lane >> 5;
    const int l32 = lane & 31;
    int dg = cursor[d]; if (dg > CAP) dg = CAP;
    const int base = d * CAP;
    const float add = ad2[d];
    float accx = 0.f, accy = 0.f, sumw = 0.f;
    for (int jj = 0; jj < dg; jj += 32) {
        int idx = jj + l32;
        if (idx >= dg) idx = dg - 1;
        const int myS = csrc[base + idx];
        // all 64 lanes compute (both halves produce identical values -> benign dup write)
        float w = 0.f;
        if (jj + l32 < dg) w = __expf(lrelu(as2[myS] + add));
        ssm[wid][l32] = myS;
        wsm[wid][l32] = w;
        int4 s0 = ((const int4*)&ssm[wid][half * 16])[0];
        int4 s1 = ((const int4*)&ssm[wid][half * 16])[1];
        int4 s2 = ((const int4*)&ssm[wid][half * 16])[2];
        int4 s3 = ((const int4*)&ssm[wid][half * 16])[3];
        int ss[16] = {s0.x, s0.y, s0.z, s0.w, s1.x, s1.y, s1.z, s1.w,
                      s2.x, s2.y, s2.z, s2.w, s3.x, s3.y, s3.z, s3.w};
        unsigned rv[16];
#pragma unroll
        for (int k = 0; k < 16; ++k)
            rv[k] = g2u[(unsigned)ss[k] * 32u + (unsigned)l32];
#pragma unroll
        for (int j = 0; j < 4; ++j) {
            float4 wf = ((const float4*)&wsm[wid][half * 16])[j];
            union { unsigned u; half2v p; } c0, c1, c2, c3;
            c0.u = rv[4 * j + 0]; c1.u = rv[4 * j + 1];
            c2.u = rv[4 * j + 2]; c3.u = rv[4 * j + 3];
            sumw += (wf.x + wf.y) + (wf.z + wf.w);
            accx += wf.x * (float)c0.p[0]; accy += wf.x * (float)c0.p[1];
            accx += wf.y * (float)c1.p[0]; accy += wf.y * (float)c1.p[1];
            accx += wf.z * (float)c2.p[0]; accy += wf.z * (float)c2.p[1];
            accx += wf.w * (float)c3.p[0]; accy += wf.w * (float)c3.p[1];
        }
    }
    accx += __shfl_xor(accx, 32, 64);
    accy += __shfl_xor(accy, 32, 64);
    sumw += __shfl_xor(sumw, 32, 64);
    if (half == 0) {
        float inv = (sumw > 0.f) ? 1.f / sumw : 0.f;
        yf[(size_t)d * 64 + l32]      = accx * inv + b2[l32];        // ch l32
        yf[(size_t)d * 64 + 32 + l32] = accy * inv + b2[l32 + 32];   // ch l32+32
    }
}

extern "C" void kernel_launch(void* const* d_in, const int* in_sizes, int n_in,
                              void* d_out, int out_size, void* d_ws, size_t ws_size,
                              hipStream_t stream) {
    const float* x    = (const float*)d_in[0];
    const int*   ei   = (const int*)d_in[1];
    const float* W1   = (const float*)d_in[2];
    const float* a_s1 = (const float*)d_in[3];
    const float* a_d1 = (const float*)d_in[4];
    const float* b1   = (const float*)d_in[5];
    const float* W2   = (const float*)d_in[6];
    const float* a_s2 = (const float*)d_in[7];
    const float* a_d2 = (const float*)d_in[8];
    const float* b2   = (const float*)d_in[9];

    const int N = in_sizes[0] / C1;
    const int E = in_sizes[1] / 2;

    auto align16 = [](size_t v) { return (v + 15) & ~(size_t)15; };
    const size_t RF   = 16;
    const size_t RCUR = align16((size_t)N * 4);           // cursor / degree
    const size_t RSRC = align16((size_t)N * CAP * 4);     // bucketed csrc
    const size_t R1   = align16((size_t)N * C1 * 4);      // h1/g2 region
    const size_t R2   = align16((size_t)N * 8 * 4);       // as1+ad1 / as2+ad2

    char* base = (char*)d_ws;
    int*  cursor = (int*)(base + RF);
    int*  csrc   = (int*)(base + RF + RCUR);
    char* R1p = base + RF + RCUR + RSRC;
    char* R2p = R1p + R1;
    char* R4p = R2p + R2;
    (void)ws_size;

    unsigned* h1 = (unsigned*)R1p;               // f16-pair dwords [N,64]
    unsigned* g2 = (unsigned*)R1p;               // f16-pair dwords [N,32] (h1 dead after msg1)
    float* as1 = (float*)R2p;
    float* ad1 = as1 + (size_t)N * 4;
    float* as2 = (float*)R2p;                    // as1/ad1 dead after msg1
    float* ad2 = as2 + N;
    unsigned* out1 = (unsigned*)R4p;             // f16-pair dwords [N,64]

    const int nbTile = (N + 63) / 64;
    const int nbWave4 = (N + 3) / 4;

    hipMemsetAsync(cursor, 0, (size_t)N * 4, stream);
    gemm1_fill_kernel<<<nbTile + NBF, 256, 0, stream>>>(x, W1, a_s1, a_d1, h1,
        as1, ad1, ei, cursor, csrc, nbTile, N, E);
    msg1_csr_kernel<<<nbWave4, 256, 0, stream>>>(cursor, csrc, (const unsigned*)h1,
        as1, ad1, b1, out1, N);
    gemm2_mfma_kernel<<<nbTile, 256, 0, stream>>>((const unsigned short*)out1, W2,
        a_s2, a_d2, g2, as2, ad2, N);
    msg2_csr_kernel<<<nbWave4, 256, 0, stream>>>(cursor, csrc, (const unsigned*)g2,
        as2, ad2, b2, (float*)d_out, N);
}